// Round 1
// baseline (1250.733 us; speedup 1.0000x reference)
//
#include <hip/hip_runtime.h>

// Problem constants (fixed by reference): B=4, S=2048 -> N_TOK=8192; IN=OUT=4096; POOLS=128; top_k=2.
#define K_DIM  4096
#define N_OUT  4096
#define N_TOK  8192
#define N_POOL 128

typedef __bf16 bf16x8 __attribute__((ext_vector_type(8)));
typedef float  f32x4  __attribute__((ext_vector_type(4)));
typedef unsigned short u16x8 __attribute__((ext_vector_type(8)));

__device__ __forceinline__ unsigned short f2bf(float f) {
    union { float f; unsigned u; } v; v.f = f;
    unsigned r = v.u + 0x7fffu + ((v.u >> 16) & 1u);   // RNE
    return (unsigned short)(r >> 16);
}
__device__ __forceinline__ float bf2f(unsigned short b) {
    union { unsigned u; float f; } v; v.u = ((unsigned)b) << 16;
    return v.f;
}

// ---------------- kernel 1: w0 fp32 -> bf16 ----------------
__global__ __launch_bounds__(256) void k_convert_w0(const float* __restrict__ w0,
                                                    unsigned short* __restrict__ w0b) {
    size_t base = ((size_t)blockIdx.x * 256 + threadIdx.x) * 8;
    float4 a = *(const float4*)(w0 + base);
    float4 b = *(const float4*)(w0 + base + 4);
    u16x8 r;
    r[0] = f2bf(a.x); r[1] = f2bf(a.y); r[2] = f2bf(a.z); r[3] = f2bf(a.w);
    r[4] = f2bf(b.x); r[5] = f2bf(b.y); r[6] = f2bf(b.z); r[7] = f2bf(b.w);
    *(u16x8*)(w0b + base) = r;
}

// ---------------- kernel 2: router (fp32 logits, top-2, bf16 x write-out, svh dots) ----------------
#define RT_TOK 16
#define RT_BK  32

__global__ __launch_bounds__(256) void k_router(const float* __restrict__ x,
                                                const float* __restrict__ wr,
                                                const float* __restrict__ svh,
                                                unsigned short* __restrict__ xb,
                                                int* __restrict__ idxp,
                                                float* __restrict__ dotp) {
    __shared__ float x_lds[RT_TOK][RT_BK];        // token-major, k inner
    __shared__ float wr_lds[RT_BK][N_POOL];       // k-major so pool reads are contiguous
    __shared__ float logits[RT_TOK][N_POOL + 2];  // +2 pad: conflict-free serial scan
    __shared__ int   sel[RT_TOK][2];

    const int tid = threadIdx.x;
    const int m0  = blockIdx.x * RT_TOK;
    const int pg  = tid & 31;   // pool group: pools 4*pg .. 4*pg+3
    const int tg  = tid >> 5;   // token group: tokens tg, tg+8

    float acc[2][4] = {{0.f,0.f,0.f,0.f},{0.f,0.f,0.f,0.f}};

    for (int k0 = 0; k0 < K_DIM; k0 += RT_BK) {
        __syncthreads();
        // stage x tile (16x32 fp32) + emit bf16 x for the GEMM/dots (each element exactly once)
        if (tid < 128) {
            int tok = tid >> 3, kq = (tid & 7) * 4;
            float4 v = *(const float4*)(x + (size_t)(m0 + tok) * K_DIM + k0 + kq);
            *(float4*)&x_lds[tok][kq] = v;
            ushort4 bb;
            bb.x = f2bf(v.x); bb.y = f2bf(v.y); bb.z = f2bf(v.z); bb.w = f2bf(v.w);
            *(ushort4*)(xb + (size_t)(m0 + tok) * K_DIM + k0 + kq) = bb;
        }
        // stage wr tile (128x32), transposed into k-major LDS
#pragma unroll
        for (int i = 0; i < 4; i++) {
            int cc = tid + 256 * i;            // 0..1023
            int p = cc >> 3, kq = (cc & 7) * 4;
            float4 v = *(const float4*)(wr + (size_t)p * K_DIM + k0 + kq);
            wr_lds[kq + 0][p] = v.x; wr_lds[kq + 1][p] = v.y;
            wr_lds[kq + 2][p] = v.z; wr_lds[kq + 3][p] = v.w;
        }
        __syncthreads();
        // 2 tokens x 4 pools per thread; float4-blocked over k
#pragma unroll
        for (int kk = 0; kk < RT_BK; kk += 4) {
            float4 xa = *(float4*)&x_lds[tg][kk];
            float4 xc = *(float4*)&x_lds[tg + 8][kk];
#pragma unroll
            for (int j = 0; j < 4; j++) {
                float4 wv = *(float4*)&wr_lds[kk + j][pg * 4];
                float a0 = (&xa.x)[j], a1 = (&xc.x)[j];
                acc[0][0] += a0 * wv.x; acc[0][1] += a0 * wv.y;
                acc[0][2] += a0 * wv.z; acc[0][3] += a0 * wv.w;
                acc[1][0] += a1 * wv.x; acc[1][1] += a1 * wv.y;
                acc[1][2] += a1 * wv.z; acc[1][3] += a1 * wv.w;
            }
        }
    }

    // dump logits to LDS
#pragma unroll
    for (int t = 0; t < 2; t++)
#pragma unroll
        for (int q = 0; q < 4; q++)
            logits[tg + 8 * t][pg * 4 + q] = acc[t][q];
    __syncthreads();

    // serial top-2 per token; strict '>' matches jax.lax.top_k tie rule (earlier index wins)
    if (tid < RT_TOK) {
        float v1 = -3.4e38f, v2 = -3.4e38f; int i1 = 0, i2 = 0;
        for (int p = 0; p < N_POOL; p++) {
            float v = logits[tid][p];
            if (v > v1)      { v2 = v1; i2 = i1; v1 = v; i1 = p; }
            else if (v > v2) { v2 = v;  i2 = p; }
        }
        sel[tid][0] = i1; sel[tid][1] = i2;
        idxp[(size_t)(m0 + tid) * 2 + 0] = i1;
        idxp[(size_t)(m0 + tid) * 2 + 1] = i2;
    }
    __syncthreads();

    // svh dots: one wave per token (4 tokens/wave round-robin); both top-2 rows share the x read
    const int wave = tid >> 6, lane = tid & 63;
    for (int s = wave; s < RT_TOK; s += 4) {
        const size_t n = (size_t)(m0 + s);
        const int e0 = sel[s][0], e1 = sel[s][1];
        float d0 = 0.f, d1 = 0.f;
#pragma unroll
        for (int it = 0; it < 8; it++) {
            const int e = (it * 64 + lane) * 8;
            u16x8 xv = *(const u16x8*)(xb + n * K_DIM + e);
            float4 s0 = *(const float4*)(svh + (size_t)e0 * K_DIM + e);
            float4 s1 = *(const float4*)(svh + (size_t)e0 * K_DIM + e + 4);
            float4 s2 = *(const float4*)(svh + (size_t)e1 * K_DIM + e);
            float4 s3 = *(const float4*)(svh + (size_t)e1 * K_DIM + e + 4);
            float x0 = bf2f(xv[0]), x1 = bf2f(xv[1]), x2 = bf2f(xv[2]), x3 = bf2f(xv[3]);
            float x4 = bf2f(xv[4]), x5 = bf2f(xv[5]), x6 = bf2f(xv[6]), x7 = bf2f(xv[7]);
            d0 += x0*s0.x + x1*s0.y + x2*s0.z + x3*s0.w + x4*s1.x + x5*s1.y + x6*s1.z + x7*s1.w;
            d1 += x0*s2.x + x1*s2.y + x2*s2.z + x3*s2.w + x4*s3.x + x5*s3.y + x6*s3.z + x7*s3.w;
        }
#pragma unroll
        for (int off = 32; off > 0; off >>= 1) {
            d0 += __shfl_down(d0, off);
            d1 += __shfl_down(d1, off);
        }
        if (lane == 0) { dotp[n * 2 + 0] = d0; dotp[n * 2 + 1] = d1; }
    }
}

// ---------------- kernel 3: bf16 MFMA GEMM (m97 structure) + fused bias/expert epilogue ----------------
// C tile 128x128, BK=64, 4 waves each owning a 64x64 quadrant (4x4 of 16x16x32 MFMA).
__global__ __launch_bounds__(256) void k_gemm(const unsigned short* __restrict__ xb,
                                              const unsigned short* __restrict__ w0b,
                                              const float* __restrict__ b0,
                                              const float* __restrict__ u,
                                              const int* __restrict__ idxp,
                                              const float* __restrict__ dotp,
                                              float* __restrict__ out) {
    __shared__ unsigned short Als[128 * 64];   // 16 KB
    __shared__ unsigned short Bls[128 * 64];   // 16 KB

    const int tid  = threadIdx.x;
    const int lane = tid & 63;
    const int wv   = tid >> 6;
    const int wm   = wv & 1, wn = wv >> 1;
    const int lrow = lane & 15, lquad = lane >> 4;
    const size_t m0 = (size_t)blockIdx.y * 128;   // token tile
    const size_t n0 = (size_t)blockIdx.x * 128;   // out-feature tile

    // staging: thread t covers LDS bytes t*16 (+ i*4096): row = t/8 + 32i, col8 = (t%8)*8
    const int srow = tid >> 3;
    const int scol = (tid & 7) * 8;
    const unsigned short* ag = xb  + (m0 + srow) * K_DIM + scol;
    const unsigned short* bg = w0b + (n0 + srow) * K_DIM + scol;
    unsigned short* al = Als + srow * 64 + scol;   // byte offset tid*16 (wave-uniform base + lane*16)
    unsigned short* bl = Bls + srow * 64 + scol;

    f32x4 acc[4][4] = {};

    for (int k0 = 0; k0 < K_DIM; k0 += 64) {
        __syncthreads();
#pragma unroll
        for (int i = 0; i < 4; i++) {
            __builtin_amdgcn_global_load_lds(
                (const __attribute__((address_space(1))) void*)(ag + (size_t)i * 32 * K_DIM + k0),
                (__attribute__((address_space(3))) void*)(al + i * 2048), 16, 0, 0);
            __builtin_amdgcn_global_load_lds(
                (const __attribute__((address_space(1))) void*)(bg + (size_t)i * 32 * K_DIM + k0),
                (__attribute__((address_space(3))) void*)(bl + i * 2048), 16, 0, 0);
        }
        __syncthreads();
#pragma unroll
        for (int ks = 0; ks < 2; ks++) {
            bf16x8 af[4], bfr[4];
#pragma unroll
            for (int t = 0; t < 4; t++)
                af[t] = *(const bf16x8*)&Als[(wm * 64 + t * 16 + lrow) * 64 + ks * 32 + lquad * 8];
#pragma unroll
            for (int t = 0; t < 4; t++)
                bfr[t] = *(const bf16x8*)&Bls[(wn * 64 + t * 16 + lrow) * 64 + ks * 32 + lquad * 8];
#pragma unroll
            for (int mt = 0; mt < 4; mt++)
#pragma unroll
                for (int nt = 0; nt < 4; nt++)
                    acc[mt][nt] = __builtin_amdgcn_mfma_f32_16x16x32_bf16(af[mt], bfr[nt], acc[mt][nt], 0, 0, 0);
        }
    }

    // epilogue: C/D layout col=lane&15, row=(lane>>4)*4+reg (m89-verified)
#pragma unroll
    for (int mt = 0; mt < 4; mt++) {
        const size_t rb = m0 + wm * 64 + mt * 16 + lquad * 4;
#pragma unroll
        for (int r = 0; r < 4; r++) {
            const size_t gm = rb + r;
            const int e0 = idxp[gm * 2 + 0], e1 = idxp[gm * 2 + 1];
            const float dd0 = dotp[gm * 2 + 0], dd1 = dotp[gm * 2 + 1];
#pragma unroll
            for (int nt = 0; nt < 4; nt++) {
                const size_t gn = n0 + wn * 64 + nt * 16 + lrow;
                float vv = acc[mt][nt][r] + b0[gn]
                         + dd0 * u[gn * N_POOL + e0] + dd1 * u[gn * N_POOL + e1];
                out[gm * N_OUT + gn] = vv;
            }
        }
    }
}

extern "C" void kernel_launch(void* const* d_in, const int* in_sizes, int n_in,
                              void* d_out, int out_size, void* d_ws, size_t ws_size,
                              hipStream_t stream) {
    const float* x   = (const float*)d_in[0];  // [8192, 4096]
    const float* w0  = (const float*)d_in[1];  // [4096, 4096]
    const float* b0  = (const float*)d_in[2];  // [4096]
    const float* wr  = (const float*)d_in[3];  // [128, 4096]
    const float* u   = (const float*)d_in[4];  // [4096, 128]
    const float* svh = (const float*)d_in[5];  // [128, 4096]
    float* out = (float*)d_out;

    // workspace layout (~96.1 MiB total)
    char* ws = (char*)d_ws;
    unsigned short* xb  = (unsigned short*)ws;                       // 8192*4096*2  = 67108864 B
    unsigned short* w0b = (unsigned short*)(ws + 67108864);          // 4096*4096*2  = 33554432 B
    int*   idxp = (int*)(ws + 100663296);                            // 8192*2*4     = 65536 B
    float* dotp = (float*)(ws + 100663296 + 65536);                  // 8192*2*4     = 65536 B

    // 1) w0 -> bf16
    k_convert_w0<<<dim3(16777216 / (256 * 8)), dim3(256), 0, stream>>>(w0, w0b);
    // 2) fp32 router + top-2 + bf16 x emission + svh dots
    k_router<<<dim3(N_TOK / RT_TOK), dim3(256), 0, stream>>>(x, wr, svh, xb, idxp, dotp);
    // 3) bf16 MFMA GEMM with fused bias + rank-one expert epilogue
    k_gemm<<<dim3(N_OUT / 128, N_TOK / 128), dim3(256), 0, stream>>>(xb, w0b, b0, u, idxp, dotp, out);
}

// Round 2
// 722.327 us; speedup vs baseline: 1.7315x; 1.7315x over previous
//
#include <hip/hip_runtime.h>

// Problem constants (fixed by reference): B=4, S=2048 -> N_TOK=8192; IN=OUT=4096; POOLS=128; top_k=2.
#define K_DIM  4096
#define N_OUT  4096
#define N_TOK  8192
#define N_POOL 128

typedef __bf16 bf16x8 __attribute__((ext_vector_type(8)));
typedef float  f32x4  __attribute__((ext_vector_type(4)));
typedef unsigned short u16x8 __attribute__((ext_vector_type(8)));

__device__ __forceinline__ unsigned short f2bf(float f) {
    union { float f; unsigned u; } v; v.f = f;
    unsigned r = v.u + 0x7fffu + ((v.u >> 16) & 1u);   // RNE
    return (unsigned short)(r >> 16);
}
__device__ __forceinline__ float bf2f(unsigned short b) {
    union { unsigned u; float f; } v; v.u = ((unsigned)b) << 16;
    return v.f;
}

// ---------------- kernel 1: w0 fp32 -> bf16 ----------------
__global__ __launch_bounds__(256) void k_convert_w0(const float* __restrict__ w0,
                                                    unsigned short* __restrict__ w0b) {
    size_t base = ((size_t)blockIdx.x * 256 + threadIdx.x) * 8;
    float4 a = *(const float4*)(w0 + base);
    float4 b = *(const float4*)(w0 + base + 4);
    u16x8 r;
    r[0] = f2bf(a.x); r[1] = f2bf(a.y); r[2] = f2bf(a.z); r[3] = f2bf(a.w);
    r[4] = f2bf(b.x); r[5] = f2bf(b.y); r[6] = f2bf(b.z); r[7] = f2bf(b.w);
    *(u16x8*)(w0b + base) = r;
}

// ---------------- kernel 1b: u [OUT,POOLS] -> uT [POOLS,OUT] (epilogue gather becomes coalesced) ----
__global__ __launch_bounds__(256) void k_transpose_u(const float* __restrict__ u,
                                                     float* __restrict__ uT) {
    __shared__ float t[32][65];
    const int o0 = blockIdx.x * 64, p0 = blockIdx.y * 32;
    const int tid = threadIdx.x;
#pragma unroll
    for (int it = 0; it < 8; it++) {
        int o = (tid >> 5) + it * 8;
        t[tid & 31][o] = u[(size_t)(o0 + o) * N_POOL + p0 + (tid & 31)];
    }
    __syncthreads();
#pragma unroll
    for (int it = 0; it < 8; it++) {
        int p = (tid >> 6) + it * 4;
        uT[(size_t)(p0 + p) * N_OUT + o0 + (tid & 63)] = t[p][tid & 63];
    }
}

// ---------------- kernel 2: router (fp32 logits, top-2, bf16 x write-out, svh dots) ----------------
// 32 tokens/block x 128 pools. Thread = (pg: 4 pools) x (tg: 4 tokens). Register prefetch of
// tile k+1 is issued before the compute on tile k (global latency hidden under the FMA block).
#define RT_TOK 32
#define RT_BK  32
#define WR_LD  132   // pad: 132*4B=528B row stride -> 16B-aligned, conflict-free float4 reads

__global__ __launch_bounds__(256) void k_router(const float* __restrict__ x,
                                                const float* __restrict__ wr,
                                                const float* __restrict__ svh,
                                                unsigned short* __restrict__ xb,
                                                int* __restrict__ idxp,
                                                float* __restrict__ dotp) {
    __shared__ float x_lds[RT_TOK][RT_BK];       // 4 KB
    __shared__ float wr_lds[RT_BK][WR_LD];       // 16.5 KB, k-major
    __shared__ float logits[RT_TOK][N_POOL + 1]; // stride 129: conflict-free scan
    __shared__ int   sel[RT_TOK][2];

    const int tid = threadIdx.x;
    const int m0  = blockIdx.x * RT_TOK;
    const int pg  = tid & 31;   // pools 4*pg..+3
    const int tg  = tid >> 5;   // tokens 4*tg..+3

    // staging roles
    const int xtok = tid >> 3, xk = (tid & 7) * 4;     // x: 32x32 tile, 1 float4/thread

    float acc[4][4] = {};
    float4 x_pf;
    float4 wr_pf[4];

    // initial prefetch (tile 0)
    x_pf = *(const float4*)(x + (size_t)(m0 + xtok) * K_DIM + xk);
#pragma unroll
    for (int i = 0; i < 4; i++) {
        int cc = tid + 256 * i, p = cc >> 3, kq = (cc & 7) * 4;
        wr_pf[i] = *(const float4*)(wr + (size_t)p * K_DIM + kq);
    }

    for (int t = 0; t < K_DIM / RT_BK; t++) {
        const int k0 = t * RT_BK;
        __syncthreads();   // previous tile's consumers done
        // write prefetched tile to LDS (+ emit bf16 x exactly once per element)
        *(float4*)&x_lds[xtok][xk] = x_pf;
        {
            ushort4 bb;
            bb.x = f2bf(x_pf.x); bb.y = f2bf(x_pf.y); bb.z = f2bf(x_pf.z); bb.w = f2bf(x_pf.w);
            *(ushort4*)(xb + (size_t)(m0 + xtok) * K_DIM + k0 + xk) = bb;
        }
#pragma unroll
        for (int i = 0; i < 4; i++) {
            int cc = tid + 256 * i, p = cc >> 3, kq = (cc & 7) * 4;
            wr_lds[kq + 0][p] = wr_pf[i].x; wr_lds[kq + 1][p] = wr_pf[i].y;
            wr_lds[kq + 2][p] = wr_pf[i].z; wr_lds[kq + 3][p] = wr_pf[i].w;
        }
        __syncthreads();
        // issue next tile's loads now; results not needed until next write phase
        if (t + 1 < K_DIM / RT_BK) {
            const int kn = k0 + RT_BK;
            x_pf = *(const float4*)(x + (size_t)(m0 + xtok) * K_DIM + kn + xk);
#pragma unroll
            for (int i = 0; i < 4; i++) {
                int cc = tid + 256 * i, p = cc >> 3, kq = (cc & 7) * 4;
                wr_pf[i] = *(const float4*)(wr + (size_t)p * K_DIM + kn + kq);
            }
        }
        // compute: 4 tokens x 4 pools, float4-blocked over k
#pragma unroll
        for (int kk = 0; kk < RT_BK; kk += 4) {
            float4 xr[4];
#pragma unroll
            for (int tt = 0; tt < 4; tt++) xr[tt] = *(float4*)&x_lds[tg * 4 + tt][kk];
#pragma unroll
            for (int j = 0; j < 4; j++) {
                float4 wv = *(float4*)&wr_lds[kk + j][pg * 4];
#pragma unroll
                for (int tt = 0; tt < 4; tt++) {
                    float a = (&xr[tt].x)[j];
                    acc[tt][0] += a * wv.x; acc[tt][1] += a * wv.y;
                    acc[tt][2] += a * wv.z; acc[tt][3] += a * wv.w;
                }
            }
        }
    }

    // logits -> LDS
    __syncthreads();
#pragma unroll
    for (int tt = 0; tt < 4; tt++)
#pragma unroll
        for (int q = 0; q < 4; q++)
            logits[tg * 4 + tt][pg * 4 + q] = acc[tt][q];
    __syncthreads();

    // serial top-2 per token; strict '>' matches jax.lax.top_k tie rule (earlier index wins)
    if (tid < RT_TOK) {
        float v1 = -3.4e38f, v2 = -3.4e38f; int i1 = 0, i2 = 0;
        for (int p = 0; p < N_POOL; p++) {
            float v = logits[tid][p];
            if (v > v1)      { v2 = v1; i2 = i1; v1 = v; i1 = p; }
            else if (v > v2) { v2 = v;  i2 = p; }
        }
        sel[tid][0] = i1; sel[tid][1] = i2;
        idxp[(size_t)(m0 + tid) * 2 + 0] = i1;
        idxp[(size_t)(m0 + tid) * 2 + 1] = i2;
    }
    __syncthreads();

    // svh dots: one wave per token (8 tokens/wave round-robin); both top-2 rows share the x read
    const int wave = tid >> 6, lane = tid & 63;
    for (int s = wave; s < RT_TOK; s += 4) {
        const size_t n = (size_t)(m0 + s);
        const int e0 = sel[s][0], e1 = sel[s][1];
        float d0 = 0.f, d1 = 0.f;
#pragma unroll
        for (int it = 0; it < 8; it++) {
            const int e = (it * 64 + lane) * 8;
            u16x8 xv = *(const u16x8*)(xb + n * K_DIM + e);
            float4 s0 = *(const float4*)(svh + (size_t)e0 * K_DIM + e);
            float4 s1 = *(const float4*)(svh + (size_t)e0 * K_DIM + e + 4);
            float4 s2 = *(const float4*)(svh + (size_t)e1 * K_DIM + e);
            float4 s3 = *(const float4*)(svh + (size_t)e1 * K_DIM + e + 4);
            float x0 = bf2f(xv[0]), x1 = bf2f(xv[1]), x2 = bf2f(xv[2]), x3 = bf2f(xv[3]);
            float x4 = bf2f(xv[4]), x5 = bf2f(xv[5]), x6 = bf2f(xv[6]), x7 = bf2f(xv[7]);
            d0 += x0*s0.x + x1*s0.y + x2*s0.z + x3*s0.w + x4*s1.x + x5*s1.y + x6*s1.z + x7*s1.w;
            d1 += x0*s2.x + x1*s2.y + x2*s2.z + x3*s2.w + x4*s3.x + x5*s3.y + x6*s3.z + x7*s3.w;
        }
#pragma unroll
        for (int off = 32; off > 0; off >>= 1) {
            d0 += __shfl_down(d0, off);
            d1 += __shfl_down(d1, off);
        }
        if (lane == 0) { dotp[n * 2 + 0] = d0; dotp[n * 2 + 1] = d1; }
    }
}

// ---------------- kernel 3: bf16 MFMA GEMM + fused bias/expert epilogue ----------------
// C tile 128x128, BK=64, 4 waves each owning a 64x64 quadrant (4x4 of 16x16x32 MFMA).
// LDS layout is XOR-swizzled at 16B-chunk granularity: logical chunk c of row r lives at
// physical chunk c ^ (r&7). The swizzle is applied on the *global source* of
// global_load_lds (LDS dest must stay lane-ordered), and inverted in the fragment reads.
// This makes each 8-lane ds_read_b128 phase cover all 32 banks (was: 8-way conflict).
__global__ __launch_bounds__(256) void k_gemm(const unsigned short* __restrict__ xb,
                                              const unsigned short* __restrict__ w0b,
                                              const float* __restrict__ b0,
                                              const float* __restrict__ uT,
                                              const int* __restrict__ idxp,
                                              const float* __restrict__ dotp,
                                              float* __restrict__ out) {
    __shared__ unsigned short Als[128 * 64];   // 16 KB
    __shared__ unsigned short Bls[128 * 64];   // 16 KB

    const int tid  = threadIdx.x;
    const int lane = tid & 63;
    const int wv   = tid >> 6;
    const int wm   = wv & 1, wn = wv >> 1;
    const int lrow = lane & 15, lquad = lane >> 4;
    const size_t m0 = (size_t)blockIdx.y * 128;   // token tile
    const size_t n0 = (size_t)blockIdx.x * 128;   // out-feature tile

    // staging: thread t fills LDS bytes t*16 (+ i*4096). Global source chunk is XOR-swizzled.
    const int srow   = tid >> 3;                       // 0..31 (+32 per i)
    const int xchunk = (tid & 7) ^ (srow & 7);         // swizzled 16B chunk within the row
    const unsigned short* ag = xb  + (m0 + srow) * K_DIM + xchunk * 8;
    const unsigned short* bg = w0b + (n0 + srow) * K_DIM + xchunk * 8;
    unsigned short* al = Als + tid * 8;                // element offset; byte offset tid*16
    unsigned short* bl = Bls + tid * 8;

    f32x4 acc[4][4] = {};

    for (int k0 = 0; k0 < K_DIM; k0 += 64) {
        __syncthreads();
#pragma unroll
        for (int i = 0; i < 4; i++) {
            __builtin_amdgcn_global_load_lds(
                (const __attribute__((address_space(1))) void*)(ag + (size_t)i * 32 * K_DIM + k0),
                (__attribute__((address_space(3))) void*)(al + i * 2048), 16, 0, 0);
            __builtin_amdgcn_global_load_lds(
                (const __attribute__((address_space(1))) void*)(bg + (size_t)i * 32 * K_DIM + k0),
                (__attribute__((address_space(3))) void*)(bl + i * 2048), 16, 0, 0);
        }
        __syncthreads();
#pragma unroll
        for (int ks = 0; ks < 2; ks++) {
            bf16x8 af[4], bfr[4];
#pragma unroll
            for (int t = 0; t < 4; t++)
                af[t] = *(const bf16x8*)&Als[(wm * 64 + t * 16 + lrow) * 64 +
                                             (((ks * 4 + lquad) ^ (lrow & 7)) * 8)];
#pragma unroll
            for (int t = 0; t < 4; t++)
                bfr[t] = *(const bf16x8*)&Bls[(wn * 64 + t * 16 + lrow) * 64 +
                                              (((ks * 4 + lquad) ^ (lrow & 7)) * 8)];
#pragma unroll
            for (int mt = 0; mt < 4; mt++)
#pragma unroll
                for (int nt = 0; nt < 4; nt++)
                    acc[mt][nt] = __builtin_amdgcn_mfma_f32_16x16x32_bf16(af[mt], bfr[nt], acc[mt][nt], 0, 0, 0);
        }
    }

    // epilogue: C/D layout col=lane&15, row=(lane>>4)*4+reg (m89-verified)
#pragma unroll
    for (int mt = 0; mt < 4; mt++) {
        const size_t rb = m0 + wm * 64 + mt * 16 + lquad * 4;
#pragma unroll
        for (int r = 0; r < 4; r++) {
            const size_t gm = rb + r;
            const int e0 = idxp[gm * 2 + 0], e1 = idxp[gm * 2 + 1];
            const float dd0 = dotp[gm * 2 + 0], dd1 = dotp[gm * 2 + 1];
#pragma unroll
            for (int nt = 0; nt < 4; nt++) {
                const size_t gn = n0 + wn * 64 + nt * 16 + lrow;
                float vv = acc[mt][nt][r] + b0[gn]
                         + dd0 * uT[(size_t)e0 * N_OUT + gn] + dd1 * uT[(size_t)e1 * N_OUT + gn];
                out[gm * N_OUT + gn] = vv;
            }
        }
    }
}

extern "C" void kernel_launch(void* const* d_in, const int* in_sizes, int n_in,
                              void* d_out, int out_size, void* d_ws, size_t ws_size,
                              hipStream_t stream) {
    const float* x   = (const float*)d_in[0];  // [8192, 4096]
    const float* w0  = (const float*)d_in[1];  // [4096, 4096]
    const float* b0  = (const float*)d_in[2];  // [4096]
    const float* wr  = (const float*)d_in[3];  // [128, 4096]
    const float* u   = (const float*)d_in[4];  // [4096, 128]
    const float* svh = (const float*)d_in[5];  // [128, 4096]
    float* out = (float*)d_out;

    // workspace layout (~98.2 MiB total)
    char* ws = (char*)d_ws;
    unsigned short* xb  = (unsigned short*)ws;                       // 8192*4096*2  = 67108864 B
    unsigned short* w0b = (unsigned short*)(ws + 67108864);          // 4096*4096*2  = 33554432 B
    int*   idxp = (int*)(ws + 100663296);                            // 8192*2*4     = 65536 B
    float* dotp = (float*)(ws + 100663296 + 65536);                  // 8192*2*4     = 65536 B
    float* uTp  = (float*)(ws + 100663296 + 131072);                 // 128*4096*4   = 2097152 B

    k_convert_w0<<<dim3(16777216 / (256 * 8)), dim3(256), 0, stream>>>(w0, w0b);
    k_transpose_u<<<dim3(N_OUT / 64, N_POOL / 32), dim3(256), 0, stream>>>(u, uTp);
    k_router<<<dim3(N_TOK / RT_TOK), dim3(256), 0, stream>>>(x, wr, svh, xb, idxp, dotp);
    k_gemm<<<dim3(N_OUT / 128, N_TOK / 128), dim3(256), 0, stream>>>(xb, w0b, b0, uTp, idxp, dotp, out);
}